// Round 14
// baseline (173.984 us; speedup 1.0000x reference)
//
#include <hip/hip_runtime.h>
#include <hip/hip_bf16.h>
#include <math.h>

#define BB 512
#define SS 128
#define NROWS (BB*SS)      // 65536
#define TMG 64             // rows per mega block (2 blocks per trajectory)
#define NBLKG (NROWS/TMG)  // 1024

__device__ __forceinline__ float leaky01(float x){ return x >= 0.f ? x : 0.1f*x; }

#define BN_INV 0.9999950000374997f
#define SELU_A 1.6732632423543772f
#define SELU_S 1.0507009873554805f

typedef __attribute__((ext_vector_type(8))) short short8;
typedef __attribute__((ext_vector_type(4))) float f32x4;

__device__ __forceinline__ unsigned short f2bf(float f) {
    unsigned int u = __float_as_uint(f);
    u += 0x7fff + ((u >> 16) & 1);          // round-to-nearest-even
    return (unsigned short)(u >> 16);
}
__device__ __forceinline__ unsigned int pk2(float a, float b) {
    __hip_bfloat162 h = __float22bfloat162_rn(make_float2(a, b));
    unsigned int u;
    __builtin_memcpy(&u, &h, 4);
    return u;
}
__device__ __forceinline__ uint2 pack4bf(float a, float b, float c, float d) {
    uint2 r; r.x = pk2(a, b); r.y = pk2(c, d); return r;
}

// LDS tiles (TM=64), row strides multiple of 128B + XOR swizzle (row&7)<<4.
__device__ __forceinline__ unsigned short* xsp(unsigned short* base, int row, int col) {
    unsigned off = (unsigned)(row*384 + col*2);   // [64][192]
    off ^= (unsigned)((row & 7) << 4);
    return (unsigned short*)((char*)base + off);
}
__device__ __forceinline__ unsigned short* h1p(unsigned short* base, int row, int col) {
    unsigned off = (unsigned)(row*1024 + col*2);  // [64][512]
    off ^= (unsigned)((row & 7) << 4);
    return (unsigned short*)((char*)base + off);
}
__device__ __forceinline__ unsigned short* xcq(unsigned short* xbase, int row, int col) {
    unsigned off = (unsigned)(row*256 + col*2);   // [64][128], separate region
    off ^= (unsigned)((row & 7) << 4);
    return (unsigned short*)((char*)xbase + off);
}

// ================= combo: weight swizzle-prep + conv1 + cnt zero =================
#define PREP_N (278528 + 32768 + 131072)   // 442368
#define PREP_BLOCKS (PREP_N/256)           // 1728
#define CONV1_BLOCKS 578                   // ceil(147968/256)

__global__ __launch_bounds__(256) void combo1_kernel(
    const float* __restrict__ w1, const float* __restrict__ w21, const float* __restrict__ fw1,
    unsigned short* __restrict__ sw1, unsigned short* __restrict__ sw21, unsigned short* __restrict__ sw3,
    const float* __restrict__ c2w_in, const float* __restrict__ c3w_in,
    float* __restrict__ w2t, float* __restrict__ w3t,
    const float* __restrict__ T, const float* __restrict__ cw,
    const float* __restrict__ cbias, const float* __restrict__ g,
    const float* __restrict__ bb, float* __restrict__ out,   // t1 channels-last [pos68][32]
    int* __restrict__ cnt)
{
    if (blockIdx.x < PREP_BLOCKS) {
        int t = blockIdx.x*256 + threadIdx.x;
        if (t < 81920) {                       // sw1: 32 ntiles x 5 ks   (w1 [156][512], pad->160)
            int j = t & 7; int r = t >> 3; int lane = r & 63; r >>= 6;
            int ks = r % 5; int nt = r / 5;
            int n = nt*16 + (lane & 15);
            int k = ks*32 + (lane >> 4)*8 + j;
            float v = (k < 156) ? w1[k*512 + n] : 0.f;
            sw1[t] = f2bf(v);
        } else if (t < 147456) {               // sw21: 8 ntiles x 16 ks  (w21 [512][128])
            int u = t - 81920;
            int j = u & 7; int r = u >> 3; int lane = r & 63; r >>= 6;
            int ks = r & 15; int nt = r >> 4;
            int d = nt*16 + (lane & 15);
            int k = ks*32 + (lane >> 4)*8 + j;
            sw21[u] = f2bf(w21[k*128 + d]);
        } else if (t < 278528) {               // sw3: 32 ntiles x 8 ks   (fw1 [256][512])
            int u = t - 147456;
            int j = u & 7; int r = u >> 3; int lane = r & 63; r >>= 6;
            int ks = r & 7; int nt = r >> 3;
            int n = nt*16 + (lane & 15);
            int k = ks*32 + (lane >> 4)*8 + j;
            sw3[u] = f2bf(fw1[k*512 + n]);
        } else if (t < 278528 + 32768) {       // w2t[oc][kk][ic]
            int u = t - 278528;
            int oc = u >> 9; int r = u & 511;
            int kk = r >> 5; int ic = r & 31;
            w2t[u] = c2w_in[oc*512 + ic*16 + kk];
        } else {                               // w3t[oc][kk][ic]
            int u = t - (278528 + 32768);
            int oc = u >> 10; int r = u & 1023;
            int kk = r >> 6; int ic = r & 63;
            w3t[u] = c3w_in[oc*1024 + ic*16 + kk];
        }
    } else if (blockIdx.x == PREP_BLOCKS + CONV1_BLOCKS) {
        if (threadIdx.x < 256) { cnt[threadIdx.x] = 0; cnt[256 + threadIdx.x] = 0; }
    } else {
        int t = (blockIdx.x - PREP_BLOCKS)*256 + threadIdx.x;
        if (t >= 32*68*68) return;
        int oc  = t & 31;
        int pos = t >> 5;
        int oy = pos / 68, ox = pos % 68;
        float acc = cbias[oc];
        #pragma unroll
        for (int ky=0; ky<5; ++ky) {
            int iy = oy*2 - 1 + ky;
            if (iy < 0 || iy >= 138) continue;
            #pragma unroll
            for (int kx=0; kx<5; ++kx) {
                int ix = ox*2 - 1 + kx;
                if (ix < 0 || ix >= 138) continue;
                acc += cw[oc*25 + ky*5 + kx] * T[iy*138 + ix];
            }
        }
        acc = acc * (g[oc]*BN_INV) + bb[oc];
        out[pos*32 + oc] = leaky01(acc);
    }
}

// ================= conv2: channels-last, 4 lanes per output (8 ic each) =================
__global__ __launch_bounds__(256) void conv2_kernel(
    const float* __restrict__ in,      // [pos68][32]
    const float* __restrict__ w2t,     // [oc][kk][ic32]
    const float* __restrict__ bias, const float* __restrict__ g,
    const float* __restrict__ bb, float* __restrict__ out)   // [pos34][64]
{
    int gid = blockIdx.x*256 + threadIdx.x;
    if (gid >= 64*34*34*4) return;
    int icg = gid & 3;
    int o   = gid >> 2;
    int oc  = o & 63;
    int pos = o >> 6;
    int oy = pos / 34, ox = pos % 34;
    float acc = 0.f;
    #pragma unroll
    for (int ky=0; ky<4; ++ky) {
        int iy = oy*2 - 1 + ky;
        if (iy < 0 || iy >= 68) continue;
        #pragma unroll
        for (int kx=0; kx<4; ++kx) {
            int ix = ox*2 - 1 + kx;
            if (ix < 0 || ix >= 68) continue;
            const float* ip = &in[(iy*68+ix)*32 + icg*8];
            const float* wp = &w2t[oc*512 + (ky*4+kx)*32 + icg*8];
            float4 i0 = *(const float4*)ip, i1 = *(const float4*)(ip+4);
            float4 w0 = *(const float4*)wp, w1v = *(const float4*)(wp+4);
            acc += i0.x*w0.x + i0.y*w0.y + i0.z*w0.z + i0.w*w0.w
                 + i1.x*w1v.x + i1.y*w1v.y + i1.z*w1v.z + i1.w*w1v.w;
        }
    }
    acc += __shfl_xor(acc, 1, 64);
    acc += __shfl_xor(acc, 2, 64);
    if (icg == 0) {
        acc = (acc + bias[oc]) * (g[oc]*BN_INV) + bb[oc];
        out[pos*64 + oc] = leaky01(acc);
    }
}

// ================= conv3: channels-last, 8 lanes per output, transposed out =================
__global__ __launch_bounds__(256) void conv3_kernel(
    const float* __restrict__ in,      // [pos34][64]
    const float* __restrict__ w3t,     // [oc][kk][ic64]
    const float* __restrict__ bias, const float* __restrict__ g,
    const float* __restrict__ bb, float* __restrict__ outT)  // [pos17][128]
{
    int gid = blockIdx.x*256 + threadIdx.x;
    if (gid >= 128*289*8) return;
    int icg = gid & 7;
    int o   = gid >> 3;
    int oc  = o & 127;
    int pos = o >> 7;
    int oy = pos / 17, ox = pos % 17;
    float acc = 0.f;
    #pragma unroll
    for (int ky=0; ky<4; ++ky) {
        int iy = oy*2 - 1 + ky;
        if (iy < 0 || iy >= 34) continue;
        #pragma unroll
        for (int kx=0; kx<4; ++kx) {
            int ix = ox*2 - 1 + kx;
            if (ix < 0 || ix >= 34) continue;
            const float* ip = &in[(iy*34+ix)*64 + icg*8];
            const float* wp = &w3t[oc*1024 + (ky*4+kx)*64 + icg*8];
            float4 i0 = *(const float4*)ip, i1 = *(const float4*)(ip+4);
            float4 w0 = *(const float4*)wp, w1v = *(const float4*)(wp+4);
            acc += i0.x*w0.x + i0.y*w0.y + i0.z*w0.z + i0.w*w0.w
                 + i1.x*w1v.x + i1.y*w1v.y + i1.z*w1v.z + i1.w*w1v.w;
        }
    }
    acc += __shfl_xor(acc, 1, 64);
    acc += __shfl_xor(acc, 2, 64);
    acc += __shfl_xor(acc, 4, 64);
    if (icg == 0) {
        acc = (acc + bias[oc]) * (g[oc]*BN_INV) + bb[oc];
        outT[pos*128 + oc] = leaky01(acc);
    }
}

// ===== cmean -> h2(selu) -> c2 -> cv, 2 trajectories per block (256 blocks = 1/CU) =====
__global__ __launch_bounds__(256) void cmh2c2_kernel(
    const float* __restrict__ t3T, const int* __restrict__ lat, const int* __restrict__ lon,
    const float* __restrict__ w1, const float* __restrict__ b1,
    const float* __restrict__ w2, const float* __restrict__ b2,
    const float* __restrict__ fw1, const float* __restrict__ fb1,
    float* __restrict__ cvb)
{
    __shared__ int   ps[128];
    __shared__ float cms[256];
    __shared__ float h2s[512];
    __shared__ float c2s[256];
    const int b0 = blockIdx.x * 2;
    const int tid = threadIdx.x;
    if (tid < 128) {
        int bl = tid >> 6, k = tid & 63;
        ps[tid] = lat[(b0+bl)*64+k]*17 + lon[(b0+bl)*64+k];
    }
    __syncthreads();
    {
        int bl = tid >> 7, d = tid & 127;
        float s = 0.f;
        #pragma unroll 8
        for (int k=0; k<64; ++k) s += t3T[ps[bl*64+k]*128 + d];
        cms[tid] = s * (1.f/64.f);
    }
    __syncthreads();
    {
        float bb0 = b1[tid];
        float a0 = bb0, a1 = bb0;
        #pragma unroll 4
        for (int k=0; k<128; ++k) {
            float w = w1[k*256 + tid];
            a0 += cms[k] * w;
            a1 += cms[128+k] * w;
        }
        h2s[tid]       = a0 > 0.f ? SELU_S*a0 : SELU_S*SELU_A*(expf(a0)-1.f);
        h2s[256 + tid] = a1 > 0.f ? SELU_S*a1 : SELU_S*SELU_A*(expf(a1)-1.f);
    }
    __syncthreads();
    {
        int bl = tid >> 7, d = tid & 127;
        float a = 0.f;
        #pragma unroll 4
        for (int k=0; k<256; ++k) a += h2s[bl*256 + k] * w2[k*128 + d];
        c2s[bl*128 + d] = a + b2[d];
    }
    __syncthreads();
    {
        float f0 = fb1[tid], f1 = fb1[tid + 256];
        float a00 = f0, a01 = f1, a10 = f0, a11 = f1;
        #pragma unroll 4
        for (int k=0; k<128; ++k) {
            float w0 = fw1[(128+k)*512 + tid];
            float w1v= fw1[(128+k)*512 + 256 + tid];
            float c0 = c2s[k], c1 = c2s[128+k];
            a00 += c0*w0; a01 += c0*w1v;
            a10 += c1*w0; a11 += c1*w1v;
        }
        cvb[b0*512 + tid]             = a00;
        cvb[b0*512 + 256 + tid]       = a01;
        cvb[(b0+1)*512 + tid]         = a10;
        cvb[(b0+1)*512 + 256 + tid]   = a11;
    }
}

// ===== mega: TM=64, 8 waves, 80KB LDS -> 2 blocks/CU; R7 pipeline; atomic pair combine =====
__global__ __launch_bounds__(512, 4) void mega_kernel(
    const int* __restrict__ roads, const float* __restrict__ ratios,
    const float* __restrict__ lengths,
    const int* __restrict__ map_u, const int* __restrict__ map_s1,
    const int* __restrict__ map_s2, const int* __restrict__ map_s3,
    const float* __restrict__ emb_u, const float* __restrict__ emb_s1,
    const float* __restrict__ emb_s2, const float* __restrict__ emb_s3,
    const unsigned short* __restrict__ sw1, const float* __restrict__ b1,
    const unsigned short* __restrict__ sw21, const float* __restrict__ b21,
    const unsigned short* __restrict__ sw3, const float* __restrict__ cvb,
    const float* __restrict__ fw21, const float* __restrict__ fb21,
    const float* __restrict__ fw22, const float* __restrict__ fb22,
    float* __restrict__ Pbuf, int* __restrict__ cnt, float* __restrict__ out)
{
    __shared__ unsigned short buf[40960];     // 81920 B = h1[64][512] (64KB) | xcs[64][128] (16KB)
    unsigned short* xcs = buf + 32768;        // byte offset 65536
    float* pmv = (float*)buf;                 // [8*64]x2 floats, aliases dead h1

    const int tid  = threadIdx.x;
    const int wid  = tid >> 6;                // 0..7
    const int lane = tid & 63;
    const int lo   = lane & 15;
    const int hi   = lane >> 4;
    const int blk  = blockIdx.x;
    const int b    = blk >> 1;
    const int r0   = blk * TMG;

    // ---- prefetch GEMM1 ks=0 A-fragments (4 ntiles/wave) ----
    short8 afc[4];
    #pragma unroll
    for (int mt=0;mt<4;++mt)
        afc[mt] = *(const short8*)&sw1[((wid*4+mt)*5 + 0)*512 + lane*8];

    // ---- gather x rows into xs [64][192] (swizzled, in h1 region) ----
    {
        int row = tid >> 3, seg = tid & 7;
        int road = roads[r0 + row];
        const float* src = emb_u + (long)map_u[road]*128 + seg*16;
        #pragma unroll
        for (int i=0;i<4;++i) {
            float4 v = *(const float4*)&src[i*4];
            *(uint2*)xsp(buf, row, seg*16 + i*4) = pack4bf(v.x, v.y, v.z, v.w);
        }
    }
    #pragma unroll
    for (int it=0; it<4; ++it) {
        int idx = tid + it*512;
        int row = idx >> 5, k2 = idx & 31;
        int road = roads[r0 + row];
        float v;
        if      (k2 < 16) v = emb_s1[map_s1[road]*16 + k2];
        else if (k2 < 24) v = emb_s2[map_s2[road]*8  + (k2-16)];
        else if (k2 < 28) v = emb_s3[map_s3[road]*4  + (k2-24)];
        else              v = 0.f;
        *xsp(buf, row, 128 + k2) = f2bf(v);
    }
    __syncthreads();          // (1) xs ready

    // ---- GEMM1: h1^T = W1 x X^T (Nout=512, K=160); 4nt x 4rt, af 1-ahead ----
    f32x4 acc1[4][4];
    {
        #pragma unroll
        for (int mt=0;mt<4;++mt)
            #pragma unroll
            for (int rt=0;rt<4;++rt) acc1[mt][rt]=(f32x4)(0.f);
        #pragma unroll
        for (int ks=0; ks<5; ++ks) {
            short8 afn[4];
            if (ks < 4) {
                #pragma unroll
                for (int mt=0;mt<4;++mt)
                    afn[mt] = *(const short8*)&sw1[((wid*4+mt)*5 + ks+1)*512 + lane*8];
            }
            const int kb = ks*32 + hi*8;
            short8 bf[4];
            #pragma unroll
            for (int rt=0;rt<4;++rt) bf[rt] = *(const short8*)xsp(buf, rt*16+lo, kb);
            #pragma unroll
            for (int mt=0;mt<4;++mt)
                #pragma unroll
                for (int rt=0;rt<4;++rt)
                    acc1[mt][rt] = __builtin_amdgcn_mfma_f32_16x16x32_bf16(afc[mt], bf[rt], acc1[mt][rt], 0,0,0);
            if (ks < 4) {
                #pragma unroll
                for (int mt=0;mt<4;++mt) afc[mt] = afn[mt];
            }
        }
    }
    __syncthreads();          // (2) xs reads complete -> overwrite region as h1

    // ---- epi1: h1 writes; prefetch GEMM2 ks=0..3 ----
    short8 a2q0, a2q1, a2q2, a2q3;
    {
        a2q0 = *(const short8*)&sw21[(wid*16 + 0)*512 + lane*8];
        a2q1 = *(const short8*)&sw21[(wid*16 + 1)*512 + lane*8];
        a2q2 = *(const short8*)&sw21[(wid*16 + 2)*512 + lane*8];
        a2q3 = *(const short8*)&sw21[(wid*16 + 3)*512 + lane*8];
        #pragma unroll
        for (int mt=0;mt<4;++mt) {
            const int nb = wid*64 + mt*16 + hi*4;
            float4 bias = *(const float4*)&b1[nb];
            const float* bp = (const float*)&bias;
            #pragma unroll
            for (int rt=0;rt<4;++rt) {
                const float* a = (const float*)&acc1[mt][rt];
                float y0 = fmaxf(a[0]+bp[0], 0.f), y1 = fmaxf(a[1]+bp[1], 0.f);
                float y2 = fmaxf(a[2]+bp[2], 0.f), y3 = fmaxf(a[3]+bp[3], 0.f);
                *(uint2*)h1p(buf, rt*16+lo, nb) = pack4bf(y0,y1,y2,y3);
            }
        }
    }
    __syncthreads();          // (3) h1 ready

    // ---- GEMM2: rho^T = W21 x h1^T (Nout=128, K=512); 1nt x 4rt, af 4-deep rotate ----
    f32x4 acc2[4];
    {
        #pragma unroll
        for (int i=0;i<4;++i) acc2[i]=(f32x4)(0.f);
        #pragma unroll
        for (int ks=0; ks<16; ++ks) {
            short8 a_use = a2q0;
            a2q0 = a2q1; a2q1 = a2q2; a2q2 = a2q3;
            if (ks < 12)
                a2q3 = *(const short8*)&sw21[(wid*16 + ks+4)*512 + lane*8];
            const int kb = ks*32 + hi*8;
            short8 bf[4];
            #pragma unroll
            for (int i=0;i<4;++i) bf[i] = *(const short8*)h1p(buf, i*16+lo, kb);
            #pragma unroll
            for (int i=0;i<4;++i)
                acc2[i] = __builtin_amdgcn_mfma_f32_16x16x32_bf16(a_use, bf[i], acc2[i], 0,0,0);
        }
    }
    // no barrier: xcs is a separate region

    // ---- epi2: write rho to xcs [64][128]; prefetch GEMM3 ks=0 ----
    short8 a3c[4];
    {
        #pragma unroll
        for (int mt=0;mt<4;++mt)
            a3c[mt] = *(const short8*)&sw3[((wid*4+mt)*8 + 0)*512 + lane*8];
        const int nb = wid*16 + hi*4;
        float4 bias = *(const float4*)&b21[nb];
        const float* bp = (const float*)&bias;
        #pragma unroll
        for (int i=0;i<4;++i) {
            const float* a = (const float*)&acc2[i];
            *(uint2*)xcq(xcs, i*16+lo, nb) =
                pack4bf(a[0]+bp[0], a[1]+bp[1], a[2]+bp[2], a[3]+bp[3]);
        }
    }
    __syncthreads();          // (4) xcs ready (also joins all h1 reads)

    // ---- GEMM3: FW1a x rho^T (Nout=512, K=128) + cv bias + fused dual dot; 4nt x 4rt ----
    float sm[4], sv[4];
    {
        f32x4 acc[4][4];
        #pragma unroll
        for (int mt=0;mt<4;++mt)
            #pragma unroll
            for (int rt=0;rt<4;++rt) acc[mt][rt]=(f32x4)(0.f);
        #pragma unroll
        for (int ks=0; ks<4; ++ks) {
            short8 a3n[4];
            if (ks < 3) {
                #pragma unroll
                for (int mt=0;mt<4;++mt)
                    a3n[mt] = *(const short8*)&sw3[((wid*4+mt)*8 + ks+1)*512 + lane*8];
            }
            const int kb = ks*32 + hi*8;
            short8 bf[4];
            #pragma unroll
            for (int rt=0;rt<4;++rt) bf[rt] = *(const short8*)xcq(xcs, rt*16+lo, kb);
            #pragma unroll
            for (int mt=0;mt<4;++mt)
                #pragma unroll
                for (int rt=0;rt<4;++rt)
                    acc[mt][rt] = __builtin_amdgcn_mfma_f32_16x16x32_bf16(a3c[mt], bf[rt], acc[mt][rt], 0,0,0);
            if (ks < 3) {
                #pragma unroll
                for (int mt=0;mt<4;++mt) a3c[mt] = a3n[mt];
            }
        }
        #pragma unroll
        for (int rt=0;rt<4;++rt){ sm[rt]=0.f; sv[rt]=0.f; }
        #pragma unroll
        for (int mt=0;mt<4;++mt) {
            const int nb = (wid*4+mt)*16 + hi*4;
            float4 bias = *(const float4*)&cvb[b*512 + nb];   // fb1 + c2@FW1b
            float4 wm   = *(const float4*)&fw21[nb];
            float4 wv   = *(const float4*)&fw22[nb];
            const float *bp=(const float*)&bias, *wmp=(const float*)&wm, *wvp=(const float*)&wv;
            #pragma unroll
            for (int rt=0;rt<4;++rt) {
                const float* a = (const float*)&acc[mt][rt];
                #pragma unroll
                for (int j=0;j<4;++j) {
                    float y = fmaxf(a[j]+bp[j], 0.f);
                    sm[rt] += y*wmp[j];
                    sv[rt] += y*wvp[j];
                }
            }
        }
        #pragma unroll
        for (int rt=0;rt<4;++rt) {
            sm[rt] += __shfl_xor(sm[rt], 16, 64); sm[rt] += __shfl_xor(sm[rt], 32, 64);
            sv[rt] += __shfl_xor(sv[rt], 16, 64); sv[rt] += __shfl_xor(sv[rt], 32, 64);
        }
    }
    // pmv aliases h1 region; all h1 reads ended at barrier (4) — write directly
    if (hi == 0) {
        #pragma unroll
        for (int rt=0;rt<4;++rt) {
            pmv[wid*64 + rt*16 + lo]       = sm[rt];
            pmv[512 + wid*64 + rt*16 + lo] = sv[rt];
        }
    }
    __syncthreads();          // (5) pmv ready

    // ---- block partials (no-max reform) + atomic pair combine ----
    if (tid < 64) {
        float s_m = 0.f, s_v = 0.f;
        #pragma unroll
        for (int w=0; w<8; ++w) {
            s_m += pmv[w*64 + tid];
            s_v += pmv[512 + w*64 + tid];
        }
        s_m += fb21[0]; s_v += fb22[0];
        int gi = r0 + tid;
        float rl = lengths[roads[gi]] * ratios[gi];
        float pl = rl;
        float p1 = rl * expf(s_m);
        float p2 = rl * rl * expf(s_v);
        #pragma unroll
        for (int off=32; off; off>>=1) {
            pl += __shfl_xor(pl, off, 64);
            p1 += __shfl_xor(p1, off, 64);
            p2 += __shfl_xor(p2, off, 64);
        }
        if (tid == 0) {
            atomicExch(&Pbuf[blk*3+0], pl);
            atomicExch(&Pbuf[blk*3+1], p1);
            atomicExch(&Pbuf[blk*3+2], p2);
            __threadfence();
            int old = atomicAdd(&cnt[b], 1);
            if (old == 1) {
                __threadfence();
                int pb = (blk^1)*3;
                float plo = atomicAdd(&Pbuf[pb+0], 0.f);
                float p1o = atomicAdd(&Pbuf[pb+1], 0.f);
                float p2o = atomicAdd(&Pbuf[pb+2], 0.f);
                float L  = pl + plo;
                float S1 = p1 + p1o;
                float S2 = p2 + p2o;
                float logl = logf(L), ls1 = logf(S1), ls2 = logf(S2);
                out[b]       = 2.f*logl - ls1;
                out[512 + b] = 6.f*logl - 3.f*ls1 - ls2;
            }
        }
    }
}

extern "C" void kernel_launch(void* const* d_in, const int* in_sizes, int n_in,
                              void* d_out, int out_size, void* d_ws, size_t ws_size,
                              hipStream_t stream) {
    const int*   roads   = (const int*)  d_in[0];
    const float* ratios  = (const float*)d_in[1];
    const float* T       = (const float*)d_in[2];
    const int*   lon_idx = (const int*)  d_in[3];
    const int*   lat_idx = (const int*)  d_in[4];
    const float* lengths = (const float*)d_in[5];
    const int*   map_u   = (const int*)  d_in[6];
    const int*   map_s1  = (const int*)  d_in[7];
    const int*   map_s2  = (const int*)  d_in[8];
    const int*   map_s3  = (const int*)  d_in[9];
    const float* emb_u   = (const float*)d_in[10];
    const float* emb_s1  = (const float*)d_in[11];
    const float* emb_s2  = (const float*)d_in[12];
    const float* emb_s3  = (const float*)d_in[13];
    const float* rho_w1  = (const float*)d_in[14];
    const float* rho_b1  = (const float*)d_in[15];
    const float* rho_w21 = (const float*)d_in[16];
    const float* rho_b21 = (const float*)d_in[17];
    const float* conv1_w = (const float*)d_in[18];
    const float* conv1_b = (const float*)d_in[19];
    const float* bn1_g   = (const float*)d_in[20];
    const float* bn1_b   = (const float*)d_in[21];
    const float* conv2_w = (const float*)d_in[22];
    const float* conv2_b = (const float*)d_in[23];
    const float* bn2_g   = (const float*)d_in[24];
    const float* bn2_b   = (const float*)d_in[25];
    const float* conv3_w = (const float*)d_in[26];
    const float* conv3_b = (const float*)d_in[27];
    const float* bn3_g   = (const float*)d_in[28];
    const float* bn3_b   = (const float*)d_in[29];
    const float* f2_w1   = (const float*)d_in[30];
    const float* f2_b1   = (const float*)d_in[31];
    const float* f2_w2   = (const float*)d_in[32];
    const float* f2_b2   = (const float*)d_in[33];
    const float* f_w1    = (const float*)d_in[34];
    const float* f_b1    = (const float*)d_in[35];
    const float* f_w21   = (const float*)d_in[36];
    const float* f_b21   = (const float*)d_in[37];
    const float* f_w22   = (const float*)d_in[38];
    const float* f_b22   = (const float*)d_in[39];

    float* ws    = (float*)d_ws;
    float* t1    = ws;              // [4624][32]  channels-last
    float* t2    = t1 + 147968;     // [1156][64]  channels-last
    float* t3T   = t2 + 73984;      // [289][128]
    float* cvb   = t3T + 36992;     // [512][512]
    float* w2t   = cvb + 262144;    // 32768
    float* w3t   = w2t + 32768;     // 131072
    float* Pbuf  = w3t + 131072;    // 1024*3
    int*   cnt   = (int*)(Pbuf + 3072);                       // 512
    unsigned short* sw1  = (unsigned short*)(cnt + 512);      // 81920
    unsigned short* sw21 = sw1 + 81920;                       // 65536
    unsigned short* sw3  = sw21 + 65536;                      // 131072

    combo1_kernel<<<PREP_BLOCKS + CONV1_BLOCKS + 1, 256, 0, stream>>>(
        rho_w1, rho_w21, f_w1, sw1, sw21, sw3,
        conv2_w, conv3_w, w2t, w3t,
        T, conv1_w, conv1_b, bn1_g, bn1_b, t1, cnt);
    conv2_kernel<<<(64*34*34*4 + 255)/256, 256, 0, stream>>>(t1, w2t, conv2_b, bn2_g, bn2_b, t2);
    conv3_kernel<<<(128*289*8 + 255)/256, 256, 0, stream>>>(t2, w3t, conv3_b, bn3_g, bn3_b, t3T);
    cmh2c2_kernel<<<256, 256, 0, stream>>>(t3T, lat_idx, lon_idx, f2_w1, f2_b1, f2_w2, f2_b2,
                                           f_w1, f_b1, cvb);
    mega_kernel<<<NBLKG, 512, 0, stream>>>(roads, ratios, lengths,
                                           map_u, map_s1, map_s2, map_s3,
                                           emb_u, emb_s1, emb_s2, emb_s3,
                                           sw1, rho_b1, sw21, rho_b21,
                                           sw3, cvb, f_w21, f_b21, f_w22, f_b22,
                                           Pbuf, cnt, (float*)d_out);
}

// Round 15
// 117.193 us; speedup vs baseline: 1.4846x; 1.4846x over previous
//
#include <hip/hip_runtime.h>
#include <hip/hip_bf16.h>
#include <math.h>

#define BB 512
#define SS 128
#define NROWS (BB*SS)      // 65536
#define TMG 128            // rows per mega block = one trajectory
#define NBLKG (NROWS/TMG)  // 512

__device__ __forceinline__ float leaky01(float x){ return x >= 0.f ? x : 0.1f*x; }

#define BN_INV 0.9999950000374997f
#define SELU_A 1.6732632423543772f
#define SELU_S 1.0507009873554805f

typedef __attribute__((ext_vector_type(8))) short short8;
typedef __attribute__((ext_vector_type(4))) float f32x4;

__device__ __forceinline__ unsigned short f2bf(float f) {
    unsigned int u = __float_as_uint(f);
    u += 0x7fff + ((u >> 16) & 1);          // round-to-nearest-even
    return (unsigned short)(u >> 16);
}
__device__ __forceinline__ unsigned int pk2(float a, float b) {
    __hip_bfloat162 h = __float22bfloat162_rn(make_float2(a, b));
    unsigned int u;
    __builtin_memcpy(&u, &h, 4);
    return u;
}
__device__ __forceinline__ uint2 pack4bf(float a, float b, float c, float d) {
    uint2 r; r.x = pk2(a, b); r.y = pk2(c, d); return r;
}

// LDS tiles, row strides multiple of 128B + XOR swizzle (row&7)<<4.
__device__ __forceinline__ unsigned short* xsp(unsigned short* base, int row, int col) {
    unsigned off = (unsigned)(row*384 + col*2);   // [128][192]
    off ^= (unsigned)((row & 7) << 4);
    return (unsigned short*)((char*)base + off);
}
__device__ __forceinline__ unsigned short* h1p(unsigned short* base, int row, int col) {
    unsigned off = (unsigned)(row*1024 + col*2);  // [128][512]
    off ^= (unsigned)((row & 7) << 4);
    return (unsigned short*)((char*)base + off);
}
__device__ __forceinline__ unsigned short* xcp(unsigned short* base, int row, int col) {
    unsigned off = (unsigned)(row*256 + col*2);   // [128][128]
    off ^= (unsigned)((row & 7) << 4);
    return (unsigned short*)((char*)base + off);
}

// ================= combo: weight swizzle-prep + conv1 =================
#define PREP_N (278528 + 32768 + 131072)   // 442368
#define PREP_BLOCKS (PREP_N/256)           // 1728
#define CONV1_BLOCKS 578                   // ceil(147968/256)

__global__ __launch_bounds__(256) void combo1_kernel(
    const float* __restrict__ w1, const float* __restrict__ w21, const float* __restrict__ fw1,
    unsigned short* __restrict__ sw1, unsigned short* __restrict__ sw21, unsigned short* __restrict__ sw3,
    const float* __restrict__ c2w_in, const float* __restrict__ c3w_in,
    float* __restrict__ w2t, float* __restrict__ w3t,
    const float* __restrict__ T, const float* __restrict__ cw,
    const float* __restrict__ cbias, const float* __restrict__ g,
    const float* __restrict__ bb, float* __restrict__ out)   // out: t1 channels-last [pos68][32]
{
    if (blockIdx.x < PREP_BLOCKS) {
        int t = blockIdx.x*256 + threadIdx.x;
        if (t < 81920) {                       // sw1: 32 ntiles x 5 ks   (w1 [156][512], pad->160)
            int j = t & 7; int r = t >> 3; int lane = r & 63; r >>= 6;
            int ks = r % 5; int nt = r / 5;
            int n = nt*16 + (lane & 15);
            int k = ks*32 + (lane >> 4)*8 + j;
            float v = (k < 156) ? w1[k*512 + n] : 0.f;
            sw1[t] = f2bf(v);
        } else if (t < 147456) {               // sw21: 8 ntiles x 16 ks  (w21 [512][128])
            int u = t - 81920;
            int j = u & 7; int r = u >> 3; int lane = r & 63; r >>= 6;
            int ks = r & 15; int nt = r >> 4;
            int d = nt*16 + (lane & 15);
            int k = ks*32 + (lane >> 4)*8 + j;
            sw21[u] = f2bf(w21[k*128 + d]);
        } else if (t < 278528) {               // sw3: 32 ntiles x 8 ks   (fw1 [256][512])
            int u = t - 147456;
            int j = u & 7; int r = u >> 3; int lane = r & 63; r >>= 6;
            int ks = r & 7; int nt = r >> 3;
            int n = nt*16 + (lane & 15);
            int k = ks*32 + (lane >> 4)*8 + j;
            sw3[u] = f2bf(fw1[k*512 + n]);
        } else if (t < 278528 + 32768) {       // w2t[oc][kk][ic]
            int u = t - 278528;
            int oc = u >> 9; int r = u & 511;
            int kk = r >> 5; int ic = r & 31;
            w2t[u] = c2w_in[oc*512 + ic*16 + kk];
        } else {                               // w3t[oc][kk][ic]
            int u = t - (278528 + 32768);
            int oc = u >> 10; int r = u & 1023;
            int kk = r >> 6; int ic = r & 63;
            w3t[u] = c3w_in[oc*1024 + ic*16 + kk];
        }
    } else {
        int t = (blockIdx.x - PREP_BLOCKS)*256 + threadIdx.x;
        if (t >= 32*68*68) return;
        int oc  = t & 31;
        int pos = t >> 5;
        int oy = pos / 68, ox = pos % 68;
        float acc = cbias[oc];
        #pragma unroll
        for (int ky=0; ky<5; ++ky) {
            int iy = oy*2 - 1 + ky;
            if (iy < 0 || iy >= 138) continue;
            #pragma unroll
            for (int kx=0; kx<5; ++kx) {
                int ix = ox*2 - 1 + kx;
                if (ix < 0 || ix >= 138) continue;
                acc += cw[oc*25 + ky*5 + kx] * T[iy*138 + ix];
            }
        }
        acc = acc * (g[oc]*BN_INV) + bb[oc];
        out[pos*32 + oc] = leaky01(acc);
    }
}

// ================= conv2: channels-last, 4 lanes per output (8 ic each) =================
__global__ __launch_bounds__(256) void conv2_kernel(
    const float* __restrict__ in,      // [pos68][32]
    const float* __restrict__ w2t,     // [oc][kk][ic32]
    const float* __restrict__ bias, const float* __restrict__ g,
    const float* __restrict__ bb, float* __restrict__ out)   // [pos34][64]
{
    int gid = blockIdx.x*256 + threadIdx.x;
    if (gid >= 64*34*34*4) return;
    int icg = gid & 3;
    int o   = gid >> 2;
    int oc  = o & 63;
    int pos = o >> 6;
    int oy = pos / 34, ox = pos % 34;
    float acc = 0.f;
    #pragma unroll
    for (int ky=0; ky<4; ++ky) {
        int iy = oy*2 - 1 + ky;
        if (iy < 0 || iy >= 68) continue;
        #pragma unroll
        for (int kx=0; kx<4; ++kx) {
            int ix = ox*2 - 1 + kx;
            if (ix < 0 || ix >= 68) continue;
            const float* ip = &in[(iy*68+ix)*32 + icg*8];
            const float* wp = &w2t[oc*512 + (ky*4+kx)*32 + icg*8];
            float4 i0 = *(const float4*)ip, i1 = *(const float4*)(ip+4);
            float4 w0 = *(const float4*)wp, w1v = *(const float4*)(wp+4);
            acc += i0.x*w0.x + i0.y*w0.y + i0.z*w0.z + i0.w*w0.w
                 + i1.x*w1v.x + i1.y*w1v.y + i1.z*w1v.z + i1.w*w1v.w;
        }
    }
    acc += __shfl_xor(acc, 1, 64);
    acc += __shfl_xor(acc, 2, 64);
    if (icg == 0) {
        acc = (acc + bias[oc]) * (g[oc]*BN_INV) + bb[oc];
        out[pos*64 + oc] = leaky01(acc);
    }
}

// ================= conv3: channels-last, 8 lanes per output, transposed out =================
__global__ __launch_bounds__(256) void conv3_kernel(
    const float* __restrict__ in,      // [pos34][64]
    const float* __restrict__ w3t,     // [oc][kk][ic64]
    const float* __restrict__ bias, const float* __restrict__ g,
    const float* __restrict__ bb, float* __restrict__ outT)  // [pos17][128]
{
    int gid = blockIdx.x*256 + threadIdx.x;
    if (gid >= 128*289*8) return;
    int icg = gid & 7;
    int o   = gid >> 3;
    int oc  = o & 127;
    int pos = o >> 7;
    int oy = pos / 17, ox = pos % 17;
    float acc = 0.f;
    #pragma unroll
    for (int ky=0; ky<4; ++ky) {
        int iy = oy*2 - 1 + ky;
        if (iy < 0 || iy >= 34) continue;
        #pragma unroll
        for (int kx=0; kx<4; ++kx) {
            int ix = ox*2 - 1 + kx;
            if (ix < 0 || ix >= 34) continue;
            const float* ip = &in[(iy*34+ix)*64 + icg*8];
            const float* wp = &w3t[oc*1024 + (ky*4+kx)*64 + icg*8];
            float4 i0 = *(const float4*)ip, i1 = *(const float4*)(ip+4);
            float4 w0 = *(const float4*)wp, w1v = *(const float4*)(wp+4);
            acc += i0.x*w0.x + i0.y*w0.y + i0.z*w0.z + i0.w*w0.w
                 + i1.x*w1v.x + i1.y*w1v.y + i1.z*w1v.z + i1.w*w1v.w;
        }
    }
    acc += __shfl_xor(acc, 1, 64);
    acc += __shfl_xor(acc, 2, 64);
    acc += __shfl_xor(acc, 4, 64);
    if (icg == 0) {
        acc = (acc + bias[oc]) * (g[oc]*BN_INV) + bb[oc];
        outT[pos*128 + oc] = leaky01(acc);
    }
}

// ===== fused cmean -> h2(selu) -> c2 -> cv[b] = c2 @ FW1[128:256] + fb1, one block per b =====
__global__ __launch_bounds__(256) void cmh2c2_kernel(
    const float* __restrict__ t3T, const int* __restrict__ lat, const int* __restrict__ lon,
    const float* __restrict__ w1, const float* __restrict__ b1,
    const float* __restrict__ w2, const float* __restrict__ b2,
    const float* __restrict__ fw1, const float* __restrict__ fb1,
    float* __restrict__ cvb)
{
    __shared__ int   ps[64];
    __shared__ float part[256];
    __shared__ float cms[128];
    __shared__ float h2s[256];
    __shared__ float c2s[128];
    const int b = blockIdx.x;
    const int tid = threadIdx.x;
    if (tid < 64) ps[tid] = lat[b*64+tid]*17 + lon[b*64+tid];
    __syncthreads();
    {
        int d = tid & 127, half = tid >> 7;
        float s = 0.f;
        #pragma unroll 8
        for (int k=0; k<32; ++k) s += t3T[ps[half*32+k]*128 + d];
        part[tid] = s;
    }
    __syncthreads();
    if (tid < 128) cms[tid] = (part[tid] + part[tid+128]) * (1.f/64.f);
    __syncthreads();
    {
        float acc = b1[tid];
        #pragma unroll 8
        for (int k=0; k<128; ++k) acc += cms[k] * w1[k*256 + tid];
        h2s[tid] = acc > 0.f ? SELU_S*acc : SELU_S*SELU_A*(expf(acc)-1.f);
    }
    __syncthreads();
    {
        int d = tid & 127, half = tid >> 7;
        float acc = 0.f;
        #pragma unroll 8
        for (int k=0; k<128; ++k) acc += h2s[half*128 + k] * w2[(half*128+k)*128 + d];
        part[tid] = acc;
    }
    __syncthreads();
    if (tid < 128) c2s[tid] = part[tid] + part[tid+128] + b2[tid];
    __syncthreads();
    {
        float a0 = fb1[tid], a1 = fb1[tid + 256];
        #pragma unroll 8
        for (int k=0; k<128; ++k) {
            float c = c2s[k];
            a0 += c * fw1[(128+k)*512 + tid];
            a1 += c * fw1[(128+k)*512 + 256 + tid];
        }
        cvb[b*512 + tid]       = a0;
        cvb[b*512 + 256 + tid] = a1;
    }
}

// ================= mega: 128 rows (one trajectory) per block, 16 waves =================
__global__ __launch_bounds__(1024, 4) void mega_kernel(
    const int* __restrict__ roads, const float* __restrict__ ratios,
    const float* __restrict__ lengths,
    const int* __restrict__ map_u, const int* __restrict__ map_s1,
    const int* __restrict__ map_s2, const int* __restrict__ map_s3,
    const float* __restrict__ emb_u, const float* __restrict__ emb_s1,
    const float* __restrict__ emb_s2, const float* __restrict__ emb_s3,
    const unsigned short* __restrict__ sw1, const float* __restrict__ b1,
    const unsigned short* __restrict__ sw21, const float* __restrict__ b21,
    const unsigned short* __restrict__ sw3, const float* __restrict__ cvb,
    const float* __restrict__ fw21, const float* __restrict__ fb21,
    const float* __restrict__ fw22, const float* __restrict__ fb22,
    float* __restrict__ out)
{
    __shared__ unsigned short buf[65536];     // 131072 B
    float* pmv = (float*)buf;                 // pm[16][128] | pv[16][128]  (16 KB)
    float* fin = (float*)buf + 4096;          // final-phase scratch

    const int tid  = threadIdx.x;
    const int wid  = tid >> 6;                // 0..15
    const int lane = tid & 63;
    const int lo   = lane & 15;
    const int hi   = lane >> 4;
    const int b    = blockIdx.x;
    const int r0   = b * TMG;
    const int nt2  = wid >> 1;                // GEMM2 ntile
    const int rh   = wid & 1;                 // GEMM2 row half

    // ---- prefetch GEMM1 ks=0,1 A-fragments ----
    short8 afp00 = *(const short8*)&sw1[((wid*2+0)*5 + 0)*512 + lane*8];
    short8 afp10 = *(const short8*)&sw1[((wid*2+1)*5 + 0)*512 + lane*8];
    short8 afp01 = *(const short8*)&sw1[((wid*2+0)*5 + 1)*512 + lane*8];
    short8 afp11 = *(const short8*)&sw1[((wid*2+1)*5 + 1)*512 + lane*8];

    // ---- gather x rows into xs [128][192] (swizzled) ----
    {
        int row = tid >> 3, seg = tid & 7;
        int road = roads[r0 + row];
        const float* src = emb_u + (long)map_u[road]*128 + seg*16;
        #pragma unroll
        for (int i=0;i<4;++i) {
            float4 v = *(const float4*)&src[i*4];
            *(uint2*)xsp(buf, row, seg*16 + i*4) = pack4bf(v.x, v.y, v.z, v.w);
        }
    }
    for (int idx = tid; idx < 128*32; idx += 1024) {
        int row = idx >> 5, k2 = idx & 31;
        int road = roads[r0 + row];
        float v;
        if      (k2 < 16) v = emb_s1[map_s1[road]*16 + k2];
        else if (k2 < 24) v = emb_s2[map_s2[road]*8  + (k2-16)];
        else if (k2 < 28) v = emb_s3[map_s3[road]*4  + (k2-24)];
        else              v = 0.f;
        *xsp(buf, row, 128 + k2) = f2bf(v);
    }
    __syncthreads();

    // ---- GEMM1: h1^T = W1 x X^T (Nout=512, K=160); af 2-ahead, bf batched ----
    f32x4 acc1[2][8];
    {
        #pragma unroll
        for (int mt=0;mt<2;++mt)
            #pragma unroll
            for (int rg=0;rg<8;++rg) acc1[mt][rg]=(f32x4)(0.f);
        short8 a0c = afp00, a1c = afp10, a0n = afp01, a1n = afp11;
        #pragma unroll
        for (int ks=0; ks<5; ++ks) {
            short8 a0f = a0c, a1f = a1c;
            if (ks < 3) {
                a0f = *(const short8*)&sw1[((wid*2+0)*5 + ks+2)*512 + lane*8];
                a1f = *(const short8*)&sw1[((wid*2+1)*5 + ks+2)*512 + lane*8];
            }
            const int kb = ks*32 + hi*8;
            short8 bf[4];
            #pragma unroll
            for (int rg=0;rg<4;++rg) bf[rg] = *(const short8*)xsp(buf, rg*16+lo, kb);
            #pragma unroll
            for (int rg=0;rg<4;++rg) {
                acc1[0][rg] = __builtin_amdgcn_mfma_f32_16x16x32_bf16(a0c, bf[rg], acc1[0][rg], 0,0,0);
                acc1[1][rg] = __builtin_amdgcn_mfma_f32_16x16x32_bf16(a1c, bf[rg], acc1[1][rg], 0,0,0);
            }
            #pragma unroll
            for (int rg=0;rg<4;++rg) bf[rg] = *(const short8*)xsp(buf, (4+rg)*16+lo, kb);
            #pragma unroll
            for (int rg=0;rg<4;++rg) {
                acc1[0][4+rg] = __builtin_amdgcn_mfma_f32_16x16x32_bf16(a0c, bf[rg], acc1[0][4+rg], 0,0,0);
                acc1[1][4+rg] = __builtin_amdgcn_mfma_f32_16x16x32_bf16(a1c, bf[rg], acc1[1][4+rg], 0,0,0);
            }
            a0c = a0n; a1c = a1n; a0n = a0f; a1n = a1f;
        }
    }
    __syncthreads();          // xs reads complete -> reuse buf as h1

    // ---- epi1: h1 writes; prefetch GEMM2 ks=0..3 ----
    short8 a2q0, a2q1, a2q2, a2q3;
    {
        a2q0 = *(const short8*)&sw21[(nt2*16 + 0)*512 + lane*8];
        a2q1 = *(const short8*)&sw21[(nt2*16 + 1)*512 + lane*8];
        a2q2 = *(const short8*)&sw21[(nt2*16 + 2)*512 + lane*8];
        a2q3 = *(const short8*)&sw21[(nt2*16 + 3)*512 + lane*8];
        const int n0 = wid * 32;
        #pragma unroll
        for (int mt=0;mt<2;++mt) {
            const int nb = n0 + mt*16 + hi*4;
            float4 bias = *(const float4*)&b1[nb];
            const float* bp = (const float*)&bias;
            #pragma unroll
            for (int rg=0;rg<8;++rg) {
                const float* a = (const float*)&acc1[mt][rg];
                float y0 = fmaxf(a[0]+bp[0], 0.f), y1 = fmaxf(a[1]+bp[1], 0.f);
                float y2 = fmaxf(a[2]+bp[2], 0.f), y3 = fmaxf(a[3]+bp[3], 0.f);
                *(uint2*)h1p(buf, rg*16+lo, nb) = pack4bf(y0,y1,y2,y3);
            }
        }
    }
    __syncthreads();          // h1 ready

    // ---- GEMM2: rho^T = W21 x h1^T (Nout=128, K=512); af 4-deep rotate ----
    f32x4 acc2[4];
    {
        #pragma unroll
        for (int i=0;i<4;++i) acc2[i]=(f32x4)(0.f);
        #pragma unroll
        for (int ks=0; ks<16; ++ks) {
            short8 a_use = a2q0;
            a2q0 = a2q1; a2q1 = a2q2; a2q2 = a2q3;
            if (ks < 12)
                a2q3 = *(const short8*)&sw21[(nt2*16 + ks+4)*512 + lane*8];
            const int kb = ks*32 + hi*8;
            short8 bf[4];
            #pragma unroll
            for (int i=0;i<4;++i) bf[i] = *(const short8*)h1p(buf, (rh*4+i)*16+lo, kb);
            #pragma unroll
            for (int i=0;i<4;++i)
                acc2[i] = __builtin_amdgcn_mfma_f32_16x16x32_bf16(a_use, bf[i], acc2[i], 0,0,0);
        }
    }
    __syncthreads();          // h1 reads complete -> reuse buf as xcs

    // ---- epi2: write rho to xcs [128][128]; prefetch GEMM3 ks=0,1 ----
    short8 a3c0, a3c1, a3n0, a3n1;
    {
        a3c0 = *(const short8*)&sw3[((wid*2+0)*8 + 0)*512 + lane*8];
        a3c1 = *(const short8*)&sw3[((wid*2+1)*8 + 0)*512 + lane*8];
        a3n0 = *(const short8*)&sw3[((wid*2+0)*8 + 1)*512 + lane*8];
        a3n1 = *(const short8*)&sw3[((wid*2+1)*8 + 1)*512 + lane*8];
        const int nb = nt2*16 + hi*4;
        float4 bias = *(const float4*)&b21[nb];
        const float* bp = (const float*)&bias;
        #pragma unroll
        for (int i=0;i<4;++i) {
            const float* a = (const float*)&acc2[i];
            *(uint2*)xcp(buf, (rh*4+i)*16+lo, nb) =
                pack4bf(a[0]+bp[0], a[1]+bp[1], a[2]+bp[2], a[3]+bp[3]);
        }
    }
    __syncthreads();          // xcs ready

    // ---- GEMM3: FW1a x rho^T (Nout=512, K=128) + cv bias + fused dual dot ----
    float sm[8], sv[8];
    {
        const int n0 = wid * 32;
        f32x4 acc[2][8];
        #pragma unroll
        for (int mt=0;mt<2;++mt)
            #pragma unroll
            for (int rg=0;rg<8;++rg) acc[mt][rg]=(f32x4)(0.f);
        #pragma unroll
        for (int ks=0; ks<4; ++ks) {
            short8 c0f = a3c0, c1f = a3c1;
            if (ks < 2) {
                c0f = *(const short8*)&sw3[((wid*2+0)*8 + ks+2)*512 + lane*8];
                c1f = *(const short8*)&sw3[((wid*2+1)*8 + ks+2)*512 + lane*8];
            }
            const int kb = ks*32 + hi*8;
            short8 bf[4];
            #pragma unroll
            for (int rg=0;rg<4;++rg) bf[rg] = *(const short8*)xcp(buf, rg*16+lo, kb);
            #pragma unroll
            for (int rg=0;rg<4;++rg) {
                acc[0][rg] = __builtin_amdgcn_mfma_f32_16x16x32_bf16(a3c0, bf[rg], acc[0][rg], 0,0,0);
                acc[1][rg] = __builtin_amdgcn_mfma_f32_16x16x32_bf16(a3c1, bf[rg], acc[1][rg], 0,0,0);
            }
            #pragma unroll
            for (int rg=0;rg<4;++rg) bf[rg] = *(const short8*)xcp(buf, (4+rg)*16+lo, kb);
            #pragma unroll
            for (int rg=0;rg<4;++rg) {
                acc[0][4+rg] = __builtin_amdgcn_mfma_f32_16x16x32_bf16(a3c0, bf[rg], acc[0][4+rg], 0,0,0);
                acc[1][4+rg] = __builtin_amdgcn_mfma_f32_16x16x32_bf16(a3c1, bf[rg], acc[1][4+rg], 0,0,0);
            }
            a3c0 = a3n0; a3c1 = a3n1; a3n0 = c0f; a3n1 = c1f;
        }
        #pragma unroll
        for (int rg=0;rg<8;++rg){ sm[rg]=0.f; sv[rg]=0.f; }
        #pragma unroll
        for (int mt=0;mt<2;++mt) {
            const int nb = n0 + mt*16 + hi*4;
            float4 bias = *(const float4*)&cvb[b*512 + nb];   // includes fb1 + c2@FW1b
            float4 wm   = *(const float4*)&fw21[nb];
            float4 wv   = *(const float4*)&fw22[nb];
            const float *bp=(const float*)&bias, *wmp=(const float*)&wm, *wvp=(const float*)&wv;
            #pragma unroll
            for (int rg=0;rg<8;++rg) {
                const float* a = (const float*)&acc[mt][rg];
                #pragma unroll
                for (int j=0;j<4;++j) {
                    float y = fmaxf(a[j]+bp[j], 0.f);
                    sm[rg] += y*wmp[j];
                    sv[rg] += y*wvp[j];
                }
            }
        }
        #pragma unroll
        for (int rg=0;rg<8;++rg) {
            sm[rg] += __shfl_xor(sm[rg], 16, 64); sm[rg] += __shfl_xor(sm[rg], 32, 64);
            sv[rg] += __shfl_xor(sv[rg], 16, 64); sv[rg] += __shfl_xor(sv[rg], 32, 64);
        }
    }
    __syncthreads();          // xcs reads complete -> reuse buf as pmv
    if (hi == 0) {
        #pragma unroll
        for (int rg=0;rg<8;++rg) {
            pmv[wid*128 + rg*16 + lo]        = sm[rg];
            pmv[2048 + wid*128 + rg*16 + lo] = sv[rg];
        }
    }
    __syncthreads();

    // ---- fused final reduction (one trajectory = this block) ----
    float rl = 0.f, am = 0.f, av = 0.f;
    if (tid < 128) {
        float s_m = 0.f, s_v = 0.f;
        #pragma unroll
        for (int w=0; w<16; ++w) {
            s_m += pmv[w*128 + tid];
            s_v += pmv[2048 + w*128 + tid];
        }
        s_m += fb21[0]; s_v += fb22[0];
        int gi = r0 + tid;
        rl = lengths[roads[gi]] * ratios[gi];
        float ws = rl;
        #pragma unroll
        for (int off=32; off; off>>=1) ws += __shfl_xor(ws, off, 64);
        if (lane == 0) fin[wid] = ws;          // wid 0,1
        am = s_m; av = s_v;
    }
    __syncthreads();
    if (tid < 128) {
        float l = fin[0] + fin[1];
        float logl = logf(l);
        float lw = logf(rl) - logl;
        am += lw; av += 2.f*lw;
        float mm = am, mv = av;
        #pragma unroll
        for (int off=32; off; off>>=1) { mm = fmaxf(mm, __shfl_xor(mm, off, 64)); mv = fmaxf(mv, __shfl_xor(mv, off, 64)); }
        if (lane == 0) { fin[2+wid] = mm; fin[4+wid] = mv; fin[8+wid] = logl; }
    }
    __syncthreads();
    if (tid < 128) {
        float mm = fmaxf(fin[2], fin[3]);
        float mv = fmaxf(fin[4], fin[5]);
        float se = expf(am - mm), sev = expf(av - mv);
        #pragma unroll
        for (int off=32; off; off>>=1) { se += __shfl_xor(se, off, 64); sev += __shfl_xor(sev, off, 64); }
        if (lane == 0) { fin[10+wid] = se; fin[12+wid] = sev; }
    }
    __syncthreads();
    if (tid == 0) {
        float mm = fmaxf(fin[2], fin[3]);
        float mv = fmaxf(fin[4], fin[5]);
        float lsem = logf(fin[10] + fin[11]) + mm;
        float lsev = logf(fin[12] + fin[13]) + mv;
        float logl = fin[8];
        out[b]       = logl - lsem;
        out[512 + b] = logl - 3.f*lsem - lsev;
    }
}

extern "C" void kernel_launch(void* const* d_in, const int* in_sizes, int n_in,
                              void* d_out, int out_size, void* d_ws, size_t ws_size,
                              hipStream_t stream) {
    const int*   roads   = (const int*)  d_in[0];
    const float* ratios  = (const float*)d_in[1];
    const float* T       = (const float*)d_in[2];
    const int*   lon_idx = (const int*)  d_in[3];
    const int*   lat_idx = (const int*)  d_in[4];
    const float* lengths = (const float*)d_in[5];
    const int*   map_u   = (const int*)  d_in[6];
    const int*   map_s1  = (const int*)  d_in[7];
    const int*   map_s2  = (const int*)  d_in[8];
    const int*   map_s3  = (const int*)  d_in[9];
    const float* emb_u   = (const float*)d_in[10];
    const float* emb_s1  = (const float*)d_in[11];
    const float* emb_s2  = (const float*)d_in[12];
    const float* emb_s3  = (const float*)d_in[13];
    const float* rho_w1  = (const float*)d_in[14];
    const float* rho_b1  = (const float*)d_in[15];
    const float* rho_w21 = (const float*)d_in[16];
    const float* rho_b21 = (const float*)d_in[17];
    const float* conv1_w = (const float*)d_in[18];
    const float* conv1_b = (const float*)d_in[19];
    const float* bn1_g   = (const float*)d_in[20];
    const float* bn1_b   = (const float*)d_in[21];
    const float* conv2_w = (const float*)d_in[22];
    const float* conv2_b = (const float*)d_in[23];
    const float* bn2_g   = (const float*)d_in[24];
    const float* bn2_b   = (const float*)d_in[25];
    const float* conv3_w = (const float*)d_in[26];
    const float* conv3_b = (const float*)d_in[27];
    const float* bn3_g   = (const float*)d_in[28];
    const float* bn3_b   = (const float*)d_in[29];
    const float* f2_w1   = (const float*)d_in[30];
    const float* f2_b1   = (const float*)d_in[31];
    const float* f2_w2   = (const float*)d_in[32];
    const float* f2_b2   = (const float*)d_in[33];
    const float* f_w1    = (const float*)d_in[34];
    const float* f_b1    = (const float*)d_in[35];
    const float* f_w21   = (const float*)d_in[36];
    const float* f_b21   = (const float*)d_in[37];
    const float* f_w22   = (const float*)d_in[38];
    const float* f_b22   = (const float*)d_in[39];

    float* ws    = (float*)d_ws;
    float* t1    = ws;              // [4624][32]  channels-last
    float* t2    = t1 + 147968;     // [1156][64]  channels-last
    float* t3T   = t2 + 73984;      // [289][128]
    float* cvb   = t3T + 36992;     // [512][512]
    float* w2t   = cvb + 262144;    // 32768
    float* w3t   = w2t + 32768;     // 131072
    unsigned short* sw1  = (unsigned short*)(w3t + 131072);  // 81920
    unsigned short* sw21 = sw1 + 81920;                      // 65536
    unsigned short* sw3  = sw21 + 65536;                     // 131072

    combo1_kernel<<<PREP_BLOCKS + CONV1_BLOCKS, 256, 0, stream>>>(
        rho_w1, rho_w21, f_w1, sw1, sw21, sw3,
        conv2_w, conv3_w, w2t, w3t,
        T, conv1_w, conv1_b, bn1_g, bn1_b, t1);
    conv2_kernel<<<(64*34*34*4 + 255)/256, 256, 0, stream>>>(t1, w2t, conv2_b, bn2_g, bn2_b, t2);
    conv3_kernel<<<(128*289*8 + 255)/256, 256, 0, stream>>>(t2, w3t, conv3_b, bn3_g, bn3_b, t3T);
    cmh2c2_kernel<<<512, 256, 0, stream>>>(t3T, lat_idx, lon_idx, f2_w1, f2_b1, f2_w2, f2_b2,
                                           f_w1, f_b1, cvb);
    mega_kernel<<<NBLKG, 1024, 0, stream>>>(roads, ratios, lengths,
                                            map_u, map_s1, map_s2, map_s3,
                                            emb_u, emb_s1, emb_s2, emb_s3,
                                            sw1, rho_b1, sw21, rho_b21,
                                            sw3, cvb, f_w21, f_b21, f_w22, f_b22,
                                            (float*)d_out);
}